// Round 1
// baseline (198.121 us; speedup 1.0000x reference)
//
#include <hip/hip_runtime.h>
#include <hip/hip_bf16.h>

// NT-Xent (SimCLR) loss, MI355X gfx950.
// loss = (1/N) * sum_i [ logsumexp_{j!=i}(sim[i,j]) - sim[i, i^B] ],
// sim = (zhat zhat^T)/TEMP, TEMP=0.5, N=8192, B=4096, D=128.
// Fixed-shift logsumexp (|sim|<=2 -> shift m=2, exp arg in [-4,0]).

#define NN 8192
#define BHALF 4096
#define DIMK 128

typedef __bf16 bf16x8 __attribute__((ext_vector_type(8)));
typedef float f32x4 __attribute__((ext_vector_type(4)));

// ---------------- Kernel A: L2-normalize rows, cast to bf16 ----------------
// One wave per row; lane loads float2 (128 floats / 64 lanes).
__global__ __launch_bounds__(256) void nt_normalize(
    const float* __restrict__ zi, const float* __restrict__ zj,
    unsigned int* __restrict__ zb_packed) {
  int row = blockIdx.x * 4 + (threadIdx.x >> 6);
  int lane = threadIdx.x & 63;
  const float* src = (row < BHALF) ? (zi + (size_t)row * DIMK)
                                   : (zj + (size_t)(row - BHALF) * DIMK);
  float2 v = ((const float2*)src)[lane];
  float ss = v.x * v.x + v.y * v.y;
#pragma unroll
  for (int off = 32; off >= 1; off >>= 1) ss += __shfl_xor(ss, off, 64);
  float rn = rsqrtf(ss);
  __hip_bfloat16 h0 = __float2bfloat16(v.x * rn);
  __hip_bfloat16 h1 = __float2bfloat16(v.y * rn);
  unsigned short u0 = *(unsigned short*)&h0;
  unsigned short u1 = *(unsigned short*)&h1;
  zb_packed[(size_t)row * (DIMK / 2) + lane] = ((unsigned int)u1 << 16) | u0;
}

// ---------------- Kernel B: streaming sim + exp accumulation ----------------
// Block = 4 waves. Wave w owns rows [rowblk*64 + w*16, +16), sweeps 256 cols
// (16 MFMA 16x16x32 tiles). Per-lane running sums in registers; one 16-lane
// shuffle reduction + global atomicAdd per wave at the end.
// A-frag: A[m=lane&15][k=quad*8+j]  (chunk c at k=c*32+quad*8 -> uint4 idx c*4+quad)
// C/D   : col=lane&15, row=quad*4+reg
__global__ __launch_bounds__(256) void nt_sim(
    const unsigned short* __restrict__ zb,
    float* __restrict__ rowsum, float* __restrict__ rowpos) {
  const int lane = threadIdx.x & 63;
  const int wave = threadIdx.x >> 6;
  const int quad = lane >> 4;
  const int t = lane & 15;
  const int row_base = blockIdx.y * 64 + wave * 16;
  const int col_block0 = blockIdx.x * 256;
  const int pair_base = row_base ^ BHALF;

  const uint4* arow = (const uint4*)(zb + (size_t)(row_base + t) * DIMK);
  bf16x8 a0 = __builtin_bit_cast(bf16x8, arow[0 * 4 + quad]);
  bf16x8 a1 = __builtin_bit_cast(bf16x8, arow[1 * 4 + quad]);
  bf16x8 a2 = __builtin_bit_cast(bf16x8, arow[2 * 4 + quad]);
  bf16x8 a3 = __builtin_bit_cast(bf16x8, arow[3 * 4 + quad]);

  float sum[4] = {0.f, 0.f, 0.f, 0.f};
  float pos[4] = {0.f, 0.f, 0.f, 0.f};
  // exp(sim-2) = exp2((2d-2)*log2e) = exp2(d*C1 - C1), C1 = 2*log2(e)
  const float C1 = 2.885390081777927f;

#pragma unroll
  for (int ct = 0; ct < 16; ++ct) {
    const int col_base = col_block0 + ct * 16;
    const uint4* brow = (const uint4*)(zb + (size_t)(col_base + t) * DIMK);
    f32x4 acc = {0.f, 0.f, 0.f, 0.f};
    acc = __builtin_amdgcn_mfma_f32_16x16x32_bf16(
        a0, __builtin_bit_cast(bf16x8, brow[0 * 4 + quad]), acc, 0, 0, 0);
    acc = __builtin_amdgcn_mfma_f32_16x16x32_bf16(
        a1, __builtin_bit_cast(bf16x8, brow[1 * 4 + quad]), acc, 0, 0, 0);
    acc = __builtin_amdgcn_mfma_f32_16x16x32_bf16(
        a2, __builtin_bit_cast(bf16x8, brow[2 * 4 + quad]), acc, 0, 0, 0);
    acc = __builtin_amdgcn_mfma_f32_16x16x32_bf16(
        a3, __builtin_bit_cast(bf16x8, brow[3 * 4 + quad]), acc, 0, 0, 0);

    if (col_base != row_base && col_base != pair_base) {
      // common path: no diagonal, no positive pair in this tile
#pragma unroll
      for (int r = 0; r < 4; ++r)
        sum[r] += __builtin_amdgcn_exp2f(fmaf(acc[r], C1, -C1));
    } else {
#pragma unroll
      for (int r = 0; r < 4; ++r) {
        int rg = row_base + quad * 4 + r;
        int cg = col_base + t;
        float e = __builtin_amdgcn_exp2f(fmaf(acc[r], C1, -C1));
        if (cg == rg) e = 0.0f;  // exclude diagonal
        sum[r] += e;
        if (cg == (rg ^ BHALF)) pos[r] += 2.0f * acc[r];  // positive logit
      }
    }
  }

#pragma unroll
  for (int off = 8; off >= 1; off >>= 1) {
#pragma unroll
    for (int r = 0; r < 4; ++r) {
      sum[r] += __shfl_xor(sum[r], off, 16);
      pos[r] += __shfl_xor(pos[r], off, 16);
    }
  }
  if (t == 0) {
#pragma unroll
    for (int r = 0; r < 4; ++r) {
      int rg = row_base + quad * 4 + r;
      atomicAdd(&rowsum[rg], sum[r]);
      if (pos[r] != 0.0f) atomicAdd(&rowpos[rg], pos[r]);
    }
  }
}

// ---------------- Kernel C: finalize ----------------
__global__ __launch_bounds__(256) void nt_finalize(
    const float* __restrict__ rowsum, const float* __restrict__ rowpos,
    float* __restrict__ out) {
  float local = 0.f;
  for (int i = threadIdx.x; i < NN; i += 256)
    local += logf(rowsum[i]) + 2.0f - rowpos[i];
#pragma unroll
  for (int off = 32; off >= 1; off >>= 1) local += __shfl_xor(local, off, 64);
  __shared__ float wsum[4];
  if ((threadIdx.x & 63) == 0) wsum[threadIdx.x >> 6] = local;
  __syncthreads();
  if (threadIdx.x == 0)
    out[0] = (wsum[0] + wsum[1] + wsum[2] + wsum[3]) * (1.0f / (float)NN);
}

extern "C" void kernel_launch(void* const* d_in, const int* in_sizes, int n_in,
                              void* d_out, int out_size, void* d_ws,
                              size_t ws_size, hipStream_t stream) {
  const float* zi = (const float*)d_in[0];
  const float* zj = (const float*)d_in[1];

  // workspace layout: zb (8192*128 bf16 = 2 MiB) | rowsum[8192] | rowpos[8192]
  unsigned short* zb = (unsigned short*)d_ws;
  float* rowsum = (float*)((char*)d_ws + (size_t)NN * DIMK * 2);
  float* rowpos = rowsum + NN;

  hipMemsetAsync(rowsum, 0, 2 * NN * sizeof(float), stream);

  nt_normalize<<<NN / 4, 256, 0, stream>>>(zi, zj, (unsigned int*)zb);

  dim3 grid(32, 128);  // 32 col-blocks x 128 row-blocks = 4096 blocks
  nt_sim<<<grid, 256, 0, stream>>>(zb, rowsum, rowpos);

  nt_finalize<<<1, 256, 0, stream>>>(rowsum, rowpos, (float*)d_out);
}

// Round 2
// 104.227 us; speedup vs baseline: 1.9009x; 1.9009x over previous
//
#include <hip/hip_runtime.h>
#include <hip/hip_bf16.h>

// NT-Xent (SimCLR) loss, MI355X gfx950.
// loss = (1/N) * sum_i [ logsumexp_{j!=i}(sim[i,j]) - sim[i, i^B] ]
// sim = (zhat zhat^T)/TEMP, TEMP=0.5, N=8192, B=4096, D=128.
// Fixed-shift logsumexp: |sim|<=2 -> lse = log(sum exp(sim-2)) + 2.
// Hot kernel is a branch-free streaming GEMM+exp: diagonal term is
// subtracted in the finalize (exp(sim_ii-2) recomputed from same bf16 data),
// positive term handled in finalize as a direct dot product.

#define NN 8192
#define BHALF 4096
#define DIMK 128

typedef __bf16 bf16x8 __attribute__((ext_vector_type(8)));
typedef float f32x4 __attribute__((ext_vector_type(4)));

// ---------------- Kernel A: L2-normalize rows, cast to bf16 ----------------
__global__ __launch_bounds__(256) void nt_normalize(
    const float* __restrict__ zi, const float* __restrict__ zj,
    unsigned int* __restrict__ zb_packed) {
  int row = blockIdx.x * 4 + (threadIdx.x >> 6);
  int lane = threadIdx.x & 63;
  const float* src = (row < BHALF) ? (zi + (size_t)row * DIMK)
                                   : (zj + (size_t)(row - BHALF) * DIMK);
  float2 v = ((const float2*)src)[lane];
  float ss = v.x * v.x + v.y * v.y;
#pragma unroll
  for (int off = 32; off >= 1; off >>= 1) ss += __shfl_xor(ss, off, 64);
  float rn = rsqrtf(ss);
  __hip_bfloat16 h0 = __float2bfloat16(v.x * rn);
  __hip_bfloat16 h1 = __float2bfloat16(v.y * rn);
  unsigned short u0 = *(unsigned short*)&h0;
  unsigned short u1 = *(unsigned short*)&h1;
  zb_packed[(size_t)row * (DIMK / 2) + lane] = ((unsigned int)u1 << 16) | u0;
}

// ---------------- Kernel B: streaming sim + exp accumulation ----------------
// Block = 4 waves x 64 rows each = 256 rows; sweeps 512 cols (32 col-tiles).
// Per col-tile: 4 B-frag loads feed 16 MFMAs (4 row-tiles x 4 K-chunks),
// 4 independent accumulation chains. No masking (diagonal fixed later).
// A-frag: A[m=lane&15][k=quad*8+j]  (uint4 idx c*4+quad covers k=c*32+quad*8..+7)
// C/D   : col=lane&15, row=quad*4+reg
__global__ __launch_bounds__(256, 2) void nt_sim(
    const unsigned short* __restrict__ zb, float* __restrict__ rowsum) {
  const int lane = threadIdx.x & 63;
  const int wave = threadIdx.x >> 6;
  const int quad = lane >> 4;
  const int t = lane & 15;
  const int row_base = blockIdx.y * 256 + wave * 64;
  const int col0 = blockIdx.x * 512;

  bf16x8 A[4][4];  // [row-tile][K-chunk]
#pragma unroll
  for (int rt = 0; rt < 4; ++rt) {
    const uint4* ar =
        (const uint4*)(zb + (size_t)(row_base + rt * 16 + t) * DIMK);
#pragma unroll
    for (int c = 0; c < 4; ++c)
      A[rt][c] = __builtin_bit_cast(bf16x8, ar[c * 4 + quad]);
  }

  float sum[4][4];
#pragma unroll
  for (int rt = 0; rt < 4; ++rt)
#pragma unroll
    for (int r = 0; r < 4; ++r) sum[rt][r] = 0.f;

  // exp(sim-2) = exp2(d*C1 - C1), d = dot, sim = 2d, C1 = 2*log2(e)
  const float C1 = 2.885390081777927f;

#pragma unroll 4
  for (int ct = 0; ct < 32; ++ct) {
    const uint4* br = (const uint4*)(zb + (size_t)(col0 + ct * 16 + t) * DIMK);
    bf16x8 Bf[4];
#pragma unroll
    for (int c = 0; c < 4; ++c)
      Bf[c] = __builtin_bit_cast(bf16x8, br[c * 4 + quad]);
    f32x4 acc[4];
#pragma unroll
    for (int rt = 0; rt < 4; ++rt) acc[rt] = (f32x4){0.f, 0.f, 0.f, 0.f};
#pragma unroll
    for (int c = 0; c < 4; ++c)
#pragma unroll
      for (int rt = 0; rt < 4; ++rt)
        acc[rt] = __builtin_amdgcn_mfma_f32_16x16x32_bf16(A[rt][c], Bf[c],
                                                          acc[rt], 0, 0, 0);
#pragma unroll
    for (int rt = 0; rt < 4; ++rt)
#pragma unroll
      for (int r = 0; r < 4; ++r)
        sum[rt][r] += __builtin_amdgcn_exp2f(fmaf(acc[rt][r], C1, -C1));
  }

  // reduce over the 16 col-lanes within each quad
#pragma unroll
  for (int off = 8; off >= 1; off >>= 1)
#pragma unroll
    for (int rt = 0; rt < 4; ++rt)
#pragma unroll
      for (int r = 0; r < 4; ++r)
        sum[rt][r] += __shfl_xor(sum[rt][r], off, 16);

  if (t == 0) {
#pragma unroll
    for (int rt = 0; rt < 4; ++rt)
#pragma unroll
      for (int r = 0; r < 4; ++r)
        atomicAdd(&rowsum[row_base + rt * 16 + quad * 4 + r], sum[rt][r]);
  }
}

// ---------------- Kernel C: finalize ----------------
// One thread per row: positive-pair dot, diagonal correction, log, reduce.
__device__ __forceinline__ float bf2f(unsigned short s) {
  unsigned int u = (unsigned int)s << 16;
  return __builtin_bit_cast(float, u);
}

__global__ __launch_bounds__(256) void nt_finalize(
    const unsigned short* __restrict__ zb, const float* __restrict__ rowsum,
    float* __restrict__ out) {
  int i = blockIdx.x * 256 + threadIdx.x;
  const uint4* za = (const uint4*)(zb + (size_t)i * DIMK);
  const uint4* zp = (const uint4*)(zb + (size_t)(i ^ BHALF) * DIMK);
  float dp = 0.f, dd = 0.f;
#pragma unroll
  for (int c = 0; c < 16; ++c) {
    uint4 ua = za[c], up = zp[c];
    const unsigned short* pa = (const unsigned short*)&ua;
    const unsigned short* pp = (const unsigned short*)&up;
#pragma unroll
    for (int k = 0; k < 8; ++k) {
      float a = bf2f(pa[k]), p = bf2f(pp[k]);
      dd = fmaf(a, a, dd);
      dp = fmaf(a, p, dp);
    }
  }
  const float C1 = 2.885390081777927f;
  float diag = __builtin_amdgcn_exp2f(fmaf(dd, C1, -C1));  // exp(sim_ii - 2)
  float v = logf(rowsum[i] - diag) + 2.0f - 2.0f * dp;
#pragma unroll
  for (int off = 32; off >= 1; off >>= 1) v += __shfl_xor(v, off, 64);
  __shared__ float wsum[4];
  if ((threadIdx.x & 63) == 0) wsum[threadIdx.x >> 6] = v;
  __syncthreads();
  if (threadIdx.x == 0)
    atomicAdd(out, (wsum[0] + wsum[1] + wsum[2] + wsum[3]) * (1.0f / (float)NN));
}

extern "C" void kernel_launch(void* const* d_in, const int* in_sizes, int n_in,
                              void* d_out, int out_size, void* d_ws,
                              size_t ws_size, hipStream_t stream) {
  const float* zi = (const float*)d_in[0];
  const float* zj = (const float*)d_in[1];

  // workspace: zb (8192*128 bf16 = 2 MiB) | rowsum[8192]
  unsigned short* zb = (unsigned short*)d_ws;
  float* rowsum = (float*)((char*)d_ws + (size_t)NN * DIMK * 2);

  hipMemsetAsync(rowsum, 0, NN * sizeof(float), stream);
  hipMemsetAsync(d_out, 0, sizeof(float), stream);

  nt_normalize<<<NN / 4, 256, 0, stream>>>(zi, zj, (unsigned int*)zb);

  dim3 grid(16, 32);  // 16 col-blocks x 512 cols, 32 row-blocks x 256 rows
  nt_sim<<<grid, 256, 0, stream>>>(zb, rowsum);

  nt_finalize<<<NN / 256, 256, 0, stream>>>(zb, rowsum, (float*)d_out);
}

// Round 3
// 84.668 us; speedup vs baseline: 2.3400x; 1.2310x over previous
//
#include <hip/hip_runtime.h>
#include <hip/hip_bf16.h>

// NT-Xent (SimCLR) loss, MI355X gfx950.
// loss = (1/N) * sum_i [ ln(S_i - exp2(C1*d_ii)) - (2/C1)*dp_i ]
//   where d = zhat.zhat^T (unit rows), C1 = 2*log2(e),
//   S_i = sum_j exp2(C1*d_ij), dp_i = C1 * d_{i, i^B}.
// zb stores sqrt(C1)*zhat in bf16, pre-swizzled into MFMA fragment order so
// every GEMM load is a coalesced 1KB global_load_dwordx4.
// Swizzle: 16B chunk for (tile=row>>4, c, lane=quad*16+t) at uint4 index
//   (tile*4+c)*64 + lane, covering row=tile*16+t, k in [c*32+quad*8, +8).

#define NN 8192
#define BHALF 4096
#define DIMK 128

typedef __bf16 bf16x8 __attribute__((ext_vector_type(8)));
typedef float f32x4 __attribute__((ext_vector_type(4)));

#define C1F 2.8853900817779268f   // 2*log2(e)
#define SCALEF 1.6986436f         // sqrt(C1)

// ---------------- Kernel A: normalize, scale by sqrt(C1), swizzle ----------
__global__ __launch_bounds__(256) void nt_normalize(
    const float* __restrict__ zi, const float* __restrict__ zj,
    unsigned int* __restrict__ zb_packed) {
  int row = blockIdx.x * 4 + (threadIdx.x >> 6);
  int lane = threadIdx.x & 63;
  const float* src = (row < BHALF) ? (zi + (size_t)row * DIMK)
                                   : (zj + (size_t)(row - BHALF) * DIMK);
  float2 v = ((const float2*)src)[lane];
  float ss = v.x * v.x + v.y * v.y;
#pragma unroll
  for (int off = 32; off >= 1; off >>= 1) ss += __shfl_xor(ss, off, 64);
  float rn = rsqrtf(ss) * SCALEF;
  __hip_bfloat16 h0 = __float2bfloat16(v.x * rn);
  __hip_bfloat16 h1 = __float2bfloat16(v.y * rn);
  unsigned int packed = ((unsigned int)(*(unsigned short*)&h1) << 16) |
                        (*(unsigned short*)&h0);
  // destination (swizzled): row = tile*16 + t; lane covers k = 2*lane, 2*lane+1
  int tile = row >> 4, t = row & 15;
  int cq = lane >> 2;               // chunk index 0..15 (= c*4 + quad)
  int c = cq >> 2, quad = cq & 3;
  size_t widx = ((size_t)((tile * 4 + c) * 64 + quad * 16 + t)) * 4 + (lane & 3);
  zb_packed[widx] = packed;
}

// ---------------- Kernel B: streaming sim + exp2 accumulation --------------
// Block = 4 waves x 64 rows = 256 rows; sweeps 512 cols (32 tiles).
// All loads coalesced 1KB; 1-deep register prefetch of next B tile.
// C/D: col=lane&15, row=quad*4+reg.
__global__ __launch_bounds__(256, 2) void nt_sim(
    const uint4* __restrict__ zbv, float* __restrict__ part) {
  const int lane = threadIdx.x & 63;
  const int wave = threadIdx.x >> 6;
  const int quad = lane >> 4;
  const int t = lane & 15;
  const int row_tile0 = blockIdx.y * 16 + wave * 4;
  const int TB0 = blockIdx.x * 32;

  bf16x8 A[4][4];  // [row-tile][K-chunk]
#pragma unroll
  for (int rt = 0; rt < 4; ++rt)
#pragma unroll
    for (int c = 0; c < 4; ++c)
      A[rt][c] = __builtin_bit_cast(
          bf16x8, zbv[(size_t)((row_tile0 + rt) * 4 + c) * 64 + lane]);

  float sum[4][4];
#pragma unroll
  for (int rt = 0; rt < 4; ++rt)
#pragma unroll
    for (int r = 0; r < 4; ++r) sum[rt][r] = 0.f;

  uint4 nb[4];
#pragma unroll
  for (int c = 0; c < 4; ++c) nb[c] = zbv[(size_t)(TB0 * 4 + c) * 64 + lane];

  for (int ct = 0; ct < 32; ++ct) {
    uint4 cb[4];
#pragma unroll
    for (int c = 0; c < 4; ++c) cb[c] = nb[c];
    // unconditional prefetch; last iter reads past zb into ws scratch (unused)
#pragma unroll
    for (int c = 0; c < 4; ++c)
      nb[c] = zbv[(size_t)((TB0 + ct + 1) * 4 + c) * 64 + lane];
    f32x4 acc[4];
#pragma unroll
    for (int rt = 0; rt < 4; ++rt) acc[rt] = (f32x4){0.f, 0.f, 0.f, 0.f};
#pragma unroll
    for (int c = 0; c < 4; ++c)
#pragma unroll
      for (int rt = 0; rt < 4; ++rt)
        acc[rt] = __builtin_amdgcn_mfma_f32_16x16x32_bf16(
            A[rt][c], __builtin_bit_cast(bf16x8, cb[c]), acc[rt], 0, 0, 0);
#pragma unroll
    for (int rt = 0; rt < 4; ++rt)
#pragma unroll
      for (int r = 0; r < 4; ++r)
        sum[rt][r] += __builtin_amdgcn_exp2f(acc[rt][r]);
  }

  // reduce over the 16 col-lanes within each quad
#pragma unroll
  for (int off = 8; off >= 1; off >>= 1)
#pragma unroll
    for (int rt = 0; rt < 4; ++rt)
#pragma unroll
      for (int r = 0; r < 4; ++r)
        sum[rt][r] += __shfl_xor(sum[rt][r], off, 16);

  if (t == 0) {
    float* dst = part + (size_t)blockIdx.x * NN;
    int row_base = row_tile0 * 16;
#pragma unroll
    for (int rt = 0; rt < 4; ++rt)
#pragma unroll
      for (int r = 0; r < 4; ++r)
        dst[row_base + rt * 16 + quad * 4 + r] = sum[rt][r];
  }
}

// ---------------- Kernel C: finalize ----------------
__device__ __forceinline__ float bf2f(unsigned short s) {
  unsigned int u = (unsigned int)s << 16;
  return __builtin_bit_cast(float, u);
}

__global__ __launch_bounds__(256) void nt_finalize(
    const uint4* __restrict__ zbv, const float* __restrict__ part,
    float* __restrict__ out) {
  int i = blockIdx.x * 256 + threadIdx.x;
  int tile = i >> 4, t = i & 15;
  int p = i ^ BHALF;
  int tilep = p >> 4;
  float S = 0.f;
#pragma unroll
  for (int k = 0; k < 16; ++k) S += part[(size_t)k * NN + i];
  float dp = 0.f, dd = 0.f;
#pragma unroll
  for (int cq = 0; cq < 16; ++cq) {
    int c = cq >> 2, q = cq & 3;
    uint4 ua = zbv[(size_t)((tile * 4 + c) * 64 + q * 16 + t)];
    uint4 up = zbv[(size_t)((tilep * 4 + c) * 64 + q * 16 + t)];
    const unsigned short* pa = (const unsigned short*)&ua;
    const unsigned short* pp = (const unsigned short*)&up;
#pragma unroll
    for (int k = 0; k < 8; ++k) {
      float a = bf2f(pa[k]), pv = bf2f(pp[k]);
      dd = fmaf(a, a, dd);
      dp = fmaf(a, pv, dp);
    }
  }
  float diag = __builtin_amdgcn_exp2f(dd);        // exp2(C1 * d_ii)
  float v = logf(S - diag) - (2.0f / C1F) * dp;   // lse_i - pos_i
#pragma unroll
  for (int off = 32; off >= 1; off >>= 1) v += __shfl_xor(v, off, 64);
  __shared__ float wsum[4];
  if ((threadIdx.x & 63) == 0) wsum[threadIdx.x >> 6] = v;
  __syncthreads();
  if (threadIdx.x == 0)
    atomicAdd(out, (wsum[0] + wsum[1] + wsum[2] + wsum[3]) * (1.0f / (float)NN));
}

extern "C" void kernel_launch(void* const* d_in, const int* in_sizes, int n_in,
                              void* d_out, int out_size, void* d_ws,
                              size_t ws_size, hipStream_t stream) {
  const float* zi = (const float*)d_in[0];
  const float* zj = (const float*)d_in[1];

  // ws: zb swizzled bf16 (2 MiB) | part[16][8192] (512 KiB)
  unsigned int* zb = (unsigned int*)d_ws;
  float* part = (float*)((char*)d_ws + (size_t)NN * DIMK * 2);

  hipMemsetAsync(d_out, 0, sizeof(float), stream);

  nt_normalize<<<NN / 4, 256, 0, stream>>>(zi, zj, zb);

  dim3 grid(16, 32);  // 16 col-blocks x 512 cols, 32 row-blocks x 256 rows
  nt_sim<<<grid, 256, 0, stream>>>((const uint4*)zb, part);

  nt_finalize<<<NN / 256, 256, 0, stream>>>((const uint4*)zb, part,
                                            (float*)d_out);
}